// Round 1
// baseline (478.673 us; speedup 1.0000x reference)
//
#include <hip/hip_runtime.h>

// Problem constants
#define BB   128   // batch
#define CI   64    // in channels
#define HH   32
#define WW   32
#define CO   128   // out channels
#define IF   576   // CI*9
#define OW   32    // conv out w
#define XH   34    // haloed H
#define XW   34    // haloed W
// x' layout: [XH][XW][CI][BB] bf16(ushort);  (h',w',c,b) with h'=h+1 halo
#define XP_CB    (CI*BB)              // 8192
#define XP_ELEMS ((size_t)XH*XW*CI*BB)  // 9,469,952
#define BK   32    // K-chunk = one MFMA K-step
#define NIT  72    // 4 locations * 18 chunks
#define LDK  40    // padded LDS row (20 dwords = 4*5 -> conflict-free b128 r/w)

using short8 = __attribute__((ext_vector_type(8))) short;
using f32x4  = __attribute__((ext_vector_type(4))) float;

__device__ __forceinline__ unsigned short f2bf(float f) {
  union { float f; unsigned int u; } v; v.f = f;
  unsigned int u = v.u;
  u = (u + 0x7FFFu + ((u >> 16) & 1u)) >> 16;   // RNE; inputs are finite
  return (unsigned short)u;
}

// ---- pass 1: x (B,C,H,W) fp32 -> x' (H+2,W+2,C,B) bf16 with zero halo ----
__global__ __launch_bounds__(256) void transpose_x(
    const float* __restrict__ x, unsigned short* __restrict__ xp) {
  const int c = blockIdx.x >> 5;   // 0..63
  const int h = blockIdx.x & 31;   // 0..31
  __shared__ __align__(16) unsigned short tile[32][136]; // 272B row: 16B-mult
  const int t = threadIdx.x;
  const int w = t & 31, b0 = t >> 5;         // b0 0..7
#pragma unroll
  for (int p = 0; p < 16; ++p) {
    int b = b0 + p * 8;
    float v = x[(((size_t)b * CI + c) * HH + h) * WW + w];
    tile[w][b] = f2bf(v);
  }
  __syncthreads();
  const int w2 = t >> 3;                 // 0..31
  const int bb = (t & 7) * 16;           // 0..112
  const unsigned short* src = &tile[w2][bb];
  unsigned short* dst = xp + ((size_t)(h + 1) * XW + (w2 + 1)) * XP_CB + c * BB + bb;
  *(uint4*)(dst)     = *(const uint4*)(src);
  *(uint4*)(dst + 8) = *(const uint4*)(src + 8);
}

// ---- pass 2: per-pooled-cell GEMMs + bias + relu + maxpool ----
__global__ __launch_bounds__(256, 1) void local_gemm_pool(
    const float* __restrict__ Wt, const float* __restrict__ bias,
    const unsigned short* __restrict__ xp, float* __restrict__ out) {
  __shared__ __align__(16) unsigned short Asl[3][BB][LDK];
  __shared__ __align__(16) unsigned short Bsl[3][CO][LDK];
  __shared__ int offs[IF];

  const int tid  = threadIdx.x;
  const int lane = tid & 63;
  const int wave = tid >> 6;

  // im2col offset LUT (in x' elements): kk -> (di*34+dj)*8192 + c*128
  for (int kk = tid; kk < IF; kk += 256) {
    int c = kk / 9, r = kk % 9, di = r / 3, dj = r % 3;
    offs[kk] = ((di * XW + dj) * CI + c) * BB;
  }

  // XCD swizzle: blockIdx%8 = XCD; keep all pw of a ph-row on one XCD so
  // output 64B lines (contiguous in pw) merge in that XCD's L2.
  const int bidx = blockIdx.x;
  const int x8 = bidx & 7, j = bidx >> 3;
  const int ph = 2 * x8 + (j >> 4), pw = j & 15;

  // staging ids: lanes run along n (B-tile, coalesced 256B) / b (A-tile)
  const int sn = tid & 127;
  const int kh = tid >> 7;       // kk-half (wave-uniform)

  // compute ids (mfma 16x16x32 layouts, HW-verified)
  const int r16 = lane & 15;
  const int q8  = (lane >> 4) * 8;
  const int m0  = (wave >> 1) * 64;
  const int n0  = (wave & 1) * 64;

  f32x4 acc[4][4] = {};
  f32x4 rmx[4][4] = {};   // relu => max >= 0, so 0-init is exact

  float          breg0[16], breg1[16];
  unsigned short areg0[16], areg1[16];

  __syncthreads();  // offs ready

  auto issue = [&](int it, float* br, unsigned short* ar) {
    const int loc = it / 18, kc = it % 18, k0 = kc * BK;
    const int oh = 2 * ph + (loc >> 1), ow = 2 * pw + (loc & 1);
    const int l  = oh * OW + ow;
    const float* wp = Wt + ((size_t)l * IF + (k0 + kh * 16)) * CO + sn;
#pragma unroll
    for (int i = 0; i < 16; ++i) br[i] = wp[(size_t)i * CO];
    const int base = (oh * XW + ow) * XP_CB + sn;
#pragma unroll
    for (int i = 0; i < 16; ++i) ar[i] = xp[base + offs[k0 + kh * 16 + i]];
  };

  auto writeLds = [&](int it, const float* br, const unsigned short* ar) {
    const int bufI = it % 3;
    const int col  = kh * 16;
#pragma unroll
    for (int p = 0; p < 2; ++p) {
      short8 vb, va;
#pragma unroll
      for (int i = 0; i < 8; ++i) {
        vb[i] = (short)f2bf(br[p * 8 + i]);
        va[i] = (short)ar[p * 8 + i];
      }
      *(short8*)&Bsl[bufI][sn][col + p * 8] = vb;  // conflict-free b128
      *(short8*)&Asl[bufI][sn][col + p * 8] = va;
    }
  };

  auto computeChunk = [&](int it) {
    const int bufI = it % 3;
    short8 af[4], bf[4];
#pragma unroll
    for (int tm = 0; tm < 4; ++tm)
      af[tm] = *(const short8*)&Asl[bufI][m0 + tm * 16 + r16][q8];
#pragma unroll
    for (int tn = 0; tn < 4; ++tn)
      bf[tn] = *(const short8*)&Bsl[bufI][n0 + tn * 16 + r16][q8];
#pragma unroll
    for (int tm = 0; tm < 4; ++tm)
#pragma unroll
      for (int tn = 0; tn < 4; ++tn)
        acc[tm][tn] = __builtin_amdgcn_mfma_f32_16x16x32_bf16(
            af[tm], bf[tn], acc[tm][tn], 0, 0, 0);
  };

  auto finishLoc = [&](int loc) {
    const int oh = 2 * ph + (loc >> 1), ow = 2 * pw + (loc & 1);
    const int l  = oh * OW + ow;
#pragma unroll
    for (int tn = 0; tn < 4; ++tn) {
      float bv = bias[l * CO + n0 + tn * 16 + r16];
#pragma unroll
      for (int tm = 0; tm < 4; ++tm)
#pragma unroll
        for (int e = 0; e < 4; ++e) {
          float v = acc[tm][tn][e] + bv;
          v = v > 0.f ? v : 0.f;
          rmx[tm][tn][e] = fmaxf(rmx[tm][tn][e], v);
          acc[tm][tn][e] = 0.f;
        }
    }
  };

  // 3-stage pipeline prologue: bufs 0,1 filled; chunk2 loads in flight (breg0)
  issue(0, breg0, areg0);
  issue(1, breg1, areg1);
  writeLds(0, breg0, areg0);
  issue(2, breg0, areg0);
  writeLds(1, breg1, areg1);
  __syncthreads();

  for (int it2 = 0; it2 < NIT; it2 += 2) {
    // even iter: set0 holds it2+2; issue it2+3 into set1
    if (it2 + 3 < NIT) issue(it2 + 3, breg1, areg1);
    computeChunk(it2);
    if (it2 + 2 < NIT) writeLds(it2 + 2, breg0, areg0);
    __syncthreads();
    // odd iter
    const int ito = it2 + 1;
    if (ito + 3 < NIT) issue(ito + 3, breg0, areg0);
    computeChunk(ito);
    if (ito + 2 < NIT) writeLds(ito + 2, breg1, areg1);
    if (ito % 18 == 17) finishLoc(ito / 18);   // loc boundaries are odd its
    __syncthreads();
  }

  // store pooled tile; C/D: col=lane&15, row=(lane>>4)*4+e
  float* op = out + (ph * 16 + pw);
#pragma unroll
  for (int tm = 0; tm < 4; ++tm)
#pragma unroll
    for (int e = 0; e < 4; ++e) {
      const int row = m0 + tm * 16 + (lane >> 4) * 4 + e;  // batch
#pragma unroll
      for (int tn = 0; tn < 4; ++tn) {
        const int col = n0 + tn * 16 + r16;                // c_out
        op[((size_t)row * CO + col) * 256] = rmx[tm][tn][e];
      }
    }
}

extern "C" void kernel_launch(void* const* d_in, const int* in_sizes, int n_in,
                              void* d_out, int out_size, void* d_ws, size_t ws_size,
                              hipStream_t stream) {
  (void)in_sizes; (void)n_in; (void)out_size; (void)ws_size;
  const float* x  = (const float*)d_in[0];
  const float* w  = (const float*)d_in[1];
  const float* bs = (const float*)d_in[2];
  float* out = (float*)d_out;
  unsigned short* xp = (unsigned short*)d_ws;   // needs 18.94 MB scratch

  hipMemsetAsync(xp, 0, XP_ELEMS * sizeof(unsigned short), stream); // zero halo
  transpose_x<<<dim3(CI * HH), dim3(256), 0, stream>>>(x, xp);
  local_gemm_pool<<<dim3(256), dim3(256), 0, stream>>>(w, bs, xp, out);
}